// Round 5
// baseline (308.762 us; speedup 1.0000x reference)
//
#include <hip/hip_runtime.h>
#include <hip/hip_bf16.h>

#define HW 16384   // 128*128

typedef unsigned short u16;
typedef unsigned int   u32;
typedef __attribute__((ext_vector_type(8))) short short8v;
typedef __attribute__((ext_vector_type(4))) float float4v;

__device__ __forceinline__ float b2f(u16 v) { return __uint_as_float((u32)v << 16); }
__device__ __forceinline__ u16 f2bf(float f) {   // RNE (cold paths)
  u32 u = __float_as_uint(f);
  u32 r = (u + 0x7fffu + ((u >> 16) & 1u)) >> 16;
  return (u16)r;
}
__device__ __forceinline__ float bflo(u32 u) { return __uint_as_float(u << 16); }
__device__ __forceinline__ float bfhi(u32 u) { return __uint_as_float(u & 0xffff0000u); }
// 1-instruction truncating pack: (hi16(b)<<16)|hi16(a)  [v_perm_b32]
__device__ __forceinline__ u32 pkt(float a, float b) {
  return __builtin_amdgcn_perm(__float_as_uint(b), __float_as_uint(a), 0x07060302u);
}
__device__ __forceinline__ u16 bft(float v) { return (u16)(__float_as_uint(v) >> 16); }  // trunc

// ---------------------------------------------------------------------------
// K0: swizzle ALL weights into MFMA-B fragment order (bf16, RNE).
//  B-frag layout: buf[((ntile*KS + ks)*64 + lane)*8 + j]
//  with o = ntile*16 + (lane&15), k = ks*32 + (lane>>4)*8 + j.
// ---------------------------------------------------------------------------
__global__ __launch_bounds__(256) void k_init(const float* __restrict__ w_dc,
                                              const float* __restrict__ w1,
                                              const float* __restrict__ w_ds,
                                              const float* __restrict__ w3,
                                              const float* __restrict__ w_off,
                                              u16* __restrict__ wTb, u16* __restrict__ wB1,
                                              u16* __restrict__ w3b, u16* __restrict__ woffb) {
  int idx = blockIdx.x * 256 + threadIdx.x;
  if (idx < 147456) {
    int ntile = idx / 18432, r = idx % 18432;
    int ks = r / 512, r2 = r % 512;
    int lane = r2 / 8, j = r2 % 8;
    int o = ntile * 16 + (lane & 15);
    int k = ks * 32 + ((lane >> 4) * 8) + j;
    int tap = k >> 7, ci = k & 127;
    wTb[idx] = f2bf(w_dc[(o * 128 + ci) * 9 + tap]);
  }
  int i1 = idx - 147456;
  if (i1 >= 0 && i1 < 65536) {
    int ntile = i1 / 4096, r = i1 % 4096;
    int ks = r / 512, r2 = r % 512;
    int lane = r2 / 8, j = r2 % 8;
    int o = ntile * 16 + (lane & 15);
    int c = ks * 32 + ((lane >> 4) * 8) + j;
    float v = (ntile < 8) ? w1[o * 256 + c] : w_ds[(o - 128) * 256 + c];
    wB1[i1] = f2bf(v);
  }
  int i2 = idx - 212992;
  if (i2 >= 0 && i2 < 16384) {
    int ntile = i2 / 2048, r = i2 % 2048;
    int ks = r / 512, r2 = r % 512;
    int lane = r2 / 8, j = r2 % 8;
    int o = ntile * 16 + (lane & 15);
    int c = ks * 32 + ((lane >> 4) * 8) + j;
    w3b[i2] = f2bf(w3[o * 128 + c]);
  }
  int i3 = idx - 229376;
  if (i3 >= 0 && i3 < 36864) {
    int ntile = i3 / 18432, r = i3 % 18432;
    int ks = r / 512, r2 = r % 512;
    int lane = r2 / 8, j = r2 % 8;
    int oc = ntile * 16 + (lane & 15);
    int k = ks * 32 + ((lane >> 4) * 8) + j;
    int tap = k >> 7, c = k & 127;
    woffb[i3] = (oc < 27) ? f2bf(w_off[oc * 1152 + c * 9 + tap]) : (u16)0;
  }
}

// ---------------------------------------------------------------------------
// K1: fused conv1+downsample MFMA GEMM. M=32 pos, N=256, K=256.
// grid (4,128,4); block 256 = 4 waves. xA pitch 266 u16 (bank-clean).
// ---------------------------------------------------------------------------
__global__ __launch_bounds__(256) void k_fused1(const float* __restrict__ x,
                                                const u16* __restrict__ wB1,
                                                const float* __restrict__ s1a, const float* __restrict__ t1a,
                                                const float* __restrict__ s1b, const float* __restrict__ t1b,
                                                const float* __restrict__ b_ds,
                                                const float* __restrict__ sd, const float* __restrict__ td,
                                                u16* __restrict__ out1,      // [b][h][w][o]
                                                u16* __restrict__ identb)    // [b][o][h][w]
{
  __shared__ __align__(16) u16 xA[32 * 266];   // [pos][c] bf16, pitch 266
  __shared__ __align__(16) u16 T1[128 * 34];   // [o][pos] transpose buffer
  const int tid = threadIdx.x;
  const int wq = blockIdx.x, h = blockIdx.y, b = blockIdx.z;
  const int wave = tid >> 6, lane = tid & 63;

  {
    const float* xb = x + (size_t)b * 256 * HW + h * 128 + wq * 32;
    u32* dst = (u32*)xA;                 // u32 pitch 133 per pos row
    int cp = tid >> 3, wg = tid & 7;
#pragma unroll
    for (int i = 0; i < 4; ++i) {
      int cpair = i * 32 + cp;           // 0..127
      int c0 = cpair * 2;
      float4 va = *(const float4*)&xb[(size_t)c0 * HW + wg * 4];
      float4 vb = *(const float4*)&xb[(size_t)(c0 + 1) * HW + wg * 4];
      int p0 = wg * 4;
      dst[(p0 + 0) * 133 + cpair] = pkt(va.x, vb.x);
      dst[(p0 + 1) * 133 + cpair] = pkt(va.y, vb.y);
      dst[(p0 + 2) * 133 + cpair] = pkt(va.z, vb.z);
      dst[(p0 + 3) * 133 + cpair] = pkt(va.w, vb.w);
    }
  }
  __syncthreads();

  const int nlo = lane & 15, kgr = lane >> 4;
  float4v acc[2][4];
#pragma unroll
  for (int mt = 0; mt < 2; ++mt)
#pragma unroll
    for (int nt = 0; nt < 4; ++nt) acc[mt][nt] = (float4v)(0.f);

  const u16* a0p = &xA[nlo * 266 + kgr * 8];
  const u16* a1p = &xA[(nlo + 16) * 266 + kgr * 8];
  const u16* bp = &wB1[(((size_t)(wave * 4) * 8) * 64 + lane) * 8];

#pragma unroll
  for (int ks = 0; ks < 8; ++ks) {
    short8v a0 = *(const short8v*)(a0p + ks * 32);
    short8v a1 = *(const short8v*)(a1p + ks * 32);
#pragma unroll
    for (int nt = 0; nt < 4; ++nt) {
      short8v bv = *(const short8v*)(bp + nt * 4096 + ks * 512);
      acc[0][nt] = __builtin_amdgcn_mfma_f32_16x16x32_bf16(a0, bv, acc[0][nt], 0, 0, 0);
      acc[1][nt] = __builtin_amdgcn_mfma_f32_16x16x32_bf16(a1, bv, acc[1][nt], 0, 0, 0);
    }
  }

  const int rbase = kgr * 4;
  if (wave < 2) {
#pragma unroll
    for (int nt = 0; nt < 4; ++nt) {
      int o = (wave * 4 + nt) * 16 + nlo;
      float sa = s1a[o], ta = t1a[o], sb = s1b[o], tb = t1b[o];
#pragma unroll
      for (int mt = 0; mt < 2; ++mt)
#pragma unroll
        for (int r = 0; r < 4; ++r) {
          float v = acc[mt][nt][r];
          v = fmaxf(sa * v + ta, 0.f);
          v = fmaxf(sb * v + tb, 0.f);
          int pos = mt * 16 + rbase + r;
          out1[((size_t)((b * 128 + h) * 128 + wq * 32 + pos)) * 128 + o] = bft(v);
        }
    }
  } else {
#pragma unroll
    for (int nt = 0; nt < 4; ++nt) {
      int og = (wave * 4 + nt) * 16 + nlo - 128;
      float sv = sd[og], tv = td[og], bv = b_ds[og];
#pragma unroll
      for (int mt = 0; mt < 2; ++mt)
#pragma unroll
        for (int r = 0; r < 4; ++r) {
          float v = sv * (acc[mt][nt][r] + bv) + tv;
          T1[og * 34 + mt * 16 + rbase + r] = bft(v);
        }
    }
  }
  __syncthreads();

  {
    int o = tid >> 1, half = tid & 1;
    const u16* src = &T1[o * 34 + half * 16];
    u32 bb[8];
#pragma unroll
    for (int i = 0; i < 8; ++i) bb[i] = *(const u32*)(src + i * 2);
    size_t g = ((size_t)((b * 128 + o) * 128 + h)) * 128 + wq * 32 + half * 16;
    *(uint4*)&identb[g] = make_uint4(bb[0], bb[1], bb[2], bb[3]);
    *(uint4*)&identb[g + 8] = make_uint4(bb[4], bb[5], bb[6], bb[7]);
  }
}

// ---------------------------------------------------------------------------
// K2: MEGA-FUSED DCNv2, v6 — K-split barrier-free tap loop, GLOBAL corners.
//  A1/A2: v4's proven R-buffer (3x18x128) + 9-tap offset conv, K-split over
//    4 waves (partials combined in A3 with bias+sigmoid).
//  A3: per-job jobtab = 4 clamped corner ELEMENT OFFSETS + 4 weights
//    (8 u32/job) — exact v1-v4 gather semantics.
//  Loop B: DCN GEMM K-SPLIT: wave w owns channels [32w,32w+32) of every tap
//    for ALL 8 n-tiles; lane builds its A-fragment in registers from 4
//    global 16B corner loads + blend. 1-tap register pipeline (load t+1
//    while blend+MFMA t). ZERO barriers across the 9 taps.
//  Reduction: 2-stage LDS combine of the 4 K-partials, bn2 fused.
//  grid (8,128,4); block 256 = 4 waves. LDS ~25.9 KB.
// ---------------------------------------------------------------------------
__global__ __launch_bounds__(256) void k_dcn(const u16* __restrict__ out1,
                                             const u16* __restrict__ wTb,
                                             const u16* __restrict__ w3b,
                                             const u16* __restrict__ woffb,
                                             const float* __restrict__ b_off,
                                             const float* __restrict__ b_dc,
                                             const float* __restrict__ s2, const float* __restrict__ t2,
                                             const float* __restrict__ s3a, const float* __restrict__ t3a,
                                             const float* __restrict__ s3b, const float* __restrict__ t3b,
                                             const u16* __restrict__ identb,
                                             float* __restrict__ out) {
  // U overlays: R = 54x134 u16 (14472 B) ; then Pp (4*8*128 f32 = 16384 B)
  // + P at byte 16384 (16 x 152 u16 = 4864 B) ; T2 (8704 B) overlays Pp.
  __shared__ __align__(16) u16 U[10624];   // 21,248 B
  __shared__ __align__(16) u32 J[1152];    //  4,608 B: offp | jobtab

  u16*   R    = U;                   // [seg*18+pos][134]
  float* offp = (float*)J;           // 2*16*32 f32 (A2 <-> A3)
  float* Pp   = (float*)U;           // 4096 f32 (reduction partials)
  u16*   P    = U + 8192;            // byte 16384; [pos][152] bf16
  float* T2   = (float*)U;           // 128*17*4 = 8704 B (epilogue)

  const int tid = threadIdx.x;
  const int wq = blockIdx.x, h = blockIdx.y, b = blockIdx.z;
  const int wave = tid >> 6, lane = tid & 63;
  const int nlo = lane & 15, kgr = lane >> 4;
  const u16* base = out1 + (size_t)b * HW * 128;
  const int w0 = wq * 16;

  // ---- A1: stage 3x18x128 neighborhood (v4-verbatim) ----
#pragma unroll
  for (int seg = 0; seg < 3; ++seg) {
    int y = h - 1 + seg;
    bool yok = (y >= 0) & (y < 128);
    for (int k = tid; k < 1152; k += 256) {
      int pos = k >> 6, cp = k & 63;
      int x = w0 - 1 + pos;
      u32 v = 0;
      if (yok & (x >= 0) & (x < 128))
        v = *(const u32*)&base[((size_t)(y * 128 + x)) * 128 + cp * 2];
      *(u32*)&R[(seg * 18 + pos) * 134 + cp * 2] = v;
    }
  }
  __syncthreads();

  // ---- A2: offset conv, all 9 taps from R, K-split over 4 waves ----
  {
    float4v oacc = (float4v)(0.f);
    const int ntile = wave & 1, kg = wave >> 1;
    const int t0 = kg ? 5 : 0, t1 = kg ? 9 : 5;
    for (int t = t0; t < t1; ++t) {
      int ty = t / 3, tx = t % 3;
      const u16* ap = &R[(ty * 18 + nlo + tx) * 134 + kgr * 8];
      const u16* bp = &woffb[(((size_t)(ntile * 36 + t * 4)) * 64 + lane) * 8];
#pragma unroll
      for (int ksl = 0; ksl < 4; ++ksl) {
        short8v a = *(const short8v*)(ap + ksl * 32);
        short8v bv = *(const short8v*)(bp + ksl * 512);
        oacc = __builtin_amdgcn_mfma_f32_16x16x32_bf16(a, bv, oacc, 0, 0, 0);
      }
    }
    int oc = ntile * 16 + nlo;
#pragma unroll
    for (int r = 0; r < 4; ++r)
      offp[(kg * 16 + kgr * 4 + r) * 32 + oc] = oacc[r];
  }
  __syncthreads();

  // ---- A3: per-job clamped corner offsets + weights -> jobtab ----
  {
    u32 c00 = 0, c01 = 0, c10 = 0, c11 = 0;
    float w00 = 0.f, w01 = 0.f, w10 = 0.f, w11 = 0.f;
    bool active = tid < 144;
    if (active) {
      int pos = tid / 9, tap = tid % 9;
      int w = w0 + pos;
      float dy  = offp[pos * 32 + tap]      + offp[512 + pos * 32 + tap]      + b_off[tap];
      float dxv = offp[pos * 32 + 9 + tap]  + offp[512 + pos * 32 + 9 + tap]  + b_off[9 + tap];
      float sg  = offp[pos * 32 + 18 + tap] + offp[512 + pos * 32 + 18 + tap] + b_off[18 + tap];
      float mk = 1.f / (1.f + __expf(-sg));
      float py = (float)(h - 1 + tap / 3) + dy;
      float px = (float)(w - 1 + tap % 3) + dxv;
      float fy = floorf(py), fx = floorf(px);
      int y0 = (int)fy, x0 = (int)fx;
      float wy = py - fy, wxf = px - fx;
      bool vy0 = (y0 >= 0) & (y0 < 128), vy1 = (y0 >= -1) & (y0 < 127);
      bool vx0 = (x0 >= 0) & (x0 < 128), vx1 = (x0 >= -1) & (x0 < 127);
      w00 = (vy0 & vx0) ? (1.f - wy) * (1.f - wxf) * mk : 0.f;
      w01 = (vy0 & vx1) ? (1.f - wy) * wxf * mk : 0.f;
      w10 = (vy1 & vx0) ? wy * (1.f - wxf) * mk : 0.f;
      w11 = (vy1 & vx1) ? wy * wxf * mk : 0.f;
      int y0c = min(max(y0, 0), 127), y1c = min(max(y0 + 1, 0), 127);
      int x0c = min(max(x0, 0), 127), x1c = min(max(x0 + 1, 0), 127);
      c00 = (u32)((y0c * 128 + x0c) * 128);
      c01 = (u32)((y0c * 128 + x1c) * 128);
      c10 = (u32)((y1c * 128 + x0c) * 128);
      c11 = (u32)((y1c * 128 + x1c) * 128);
    }
    __syncthreads();                        // all offp reads done
    if (active) {
      u32* jt = &J[tid * 8];
      jt[0] = c00; jt[1] = c01; jt[2] = c10; jt[3] = c11;
      ((float*)jt)[4] = w00; ((float*)jt)[5] = w01;
      ((float*)jt)[6] = w10; ((float*)jt)[7] = w11;
    }
  }
  __syncthreads();

  // ---- Loop B: DCN conv, K-split (wave = channel slice), ZERO barriers ----
  float4v acc8[8];
#pragma unroll
  for (int nt = 0; nt < 8; ++nt) acc8[nt] = (float4v)(0.f);
  {
    const int ch0 = wave * 32 + kgr * 8;    // this lane's 8-channel group
    const int jrow = nlo * 9;               // jobs of pos = nlo

    u32 gA[16], gB[16];
    float4 wA, wB;
    // tap-0 loads
    {
      uint4 co = *(const uint4*)&J[jrow * 8];
      wA = *(const float4*)&J[jrow * 8 + 4];
      uint4 v0 = *(const uint4*)(base + co.x + ch0);
      uint4 v1 = *(const uint4*)(base + co.y + ch0);
      uint4 v2 = *(const uint4*)(base + co.z + ch0);
      uint4 v3 = *(const uint4*)(base + co.w + ch0);
      gA[0] = v0.x; gA[1] = v0.y; gA[2] = v0.z; gA[3] = v0.w;
      gA[4] = v1.x; gA[5] = v1.y; gA[6] = v1.z; gA[7] = v1.w;
      gA[8] = v2.x; gA[9] = v2.y; gA[10] = v2.z; gA[11] = v2.w;
      gA[12] = v3.x; gA[13] = v3.y; gA[14] = v3.z; gA[15] = v3.w;
    }
#pragma unroll
    for (int t = 0; t < 9; ++t) {
      // issue tap t+1 corner loads into the other register set
      if (t < 8) {
        uint4 co = *(const uint4*)&J[(jrow + t + 1) * 8];
        if ((t & 1) == 0) {
          wB = *(const float4*)&J[(jrow + t + 1) * 8 + 4];
          uint4 v0 = *(const uint4*)(base + co.x + ch0);
          uint4 v1 = *(const uint4*)(base + co.y + ch0);
          uint4 v2 = *(const uint4*)(base + co.z + ch0);
          uint4 v3 = *(const uint4*)(base + co.w + ch0);
          gB[0] = v0.x; gB[1] = v0.y; gB[2] = v0.z; gB[3] = v0.w;
          gB[4] = v1.x; gB[5] = v1.y; gB[6] = v1.z; gB[7] = v1.w;
          gB[8] = v2.x; gB[9] = v2.y; gB[10] = v2.z; gB[11] = v2.w;
          gB[12] = v3.x; gB[13] = v3.y; gB[14] = v3.z; gB[15] = v3.w;
        } else {
          wA = *(const float4*)&J[(jrow + t + 1) * 8 + 4];
          uint4 v0 = *(const uint4*)(base + co.x + ch0);
          uint4 v1 = *(const uint4*)(base + co.y + ch0);
          uint4 v2 = *(const uint4*)(base + co.z + ch0);
          uint4 v3 = *(const uint4*)(base + co.w + ch0);
          gA[0] = v0.x; gA[1] = v0.y; gA[2] = v0.z; gA[3] = v0.w;
          gA[4] = v1.x; gA[5] = v1.y; gA[6] = v1.z; gA[7] = v1.w;
          gA[8] = v2.x; gA[9] = v2.y; gA[10] = v2.z; gA[11] = v2.w;
          gA[12] = v3.x; gA[13] = v3.y; gA[14] = v3.z; gA[15] = v3.w;
        }
      }
      // blend current tap -> A-fragment (channels ch0..ch0+7)
      union { u32 u[4]; short8v s; } av;
      {
        const u32* g = ((t & 1) == 0) ? gA : gB;
        float4 w = ((t & 1) == 0) ? wA : wB;
#pragma unroll
        for (int p = 0; p < 4; ++p) {
          float alo = w.x * bflo(g[p])      + w.y * bflo(g[4 + p])
                    + w.z * bflo(g[8 + p])  + w.w * bflo(g[12 + p]);
          float ahi = w.x * bfhi(g[p])      + w.y * bfhi(g[4 + p])
                    + w.z * bfhi(g[8 + p])  + w.w * bfhi(g[12 + p]);
          av.u[p] = pkt(alo, ahi);
        }
      }
      // MFMA: this wave's k-slice (ks = t*4 + wave) for all 8 n-tiles
      {
        const u16* bb = &wTb[(((size_t)(t * 4 + wave)) * 64 + lane) * 8];
#pragma unroll
        for (int nt = 0; nt < 8; ++nt) {
          short8v bv = *(const short8v*)(bb + (size_t)nt * 18432);
          acc8[nt] = __builtin_amdgcn_mfma_f32_16x16x32_bf16(av.s, bv, acc8[nt], 0, 0, 0);
        }
      }
    }
  }
  __syncthreads();   // all waves done with jobtab/R before U reuse

  // ---- Reduction: combine 4 K-partials + bn2 + relu -> P[pos][o] bf16 ----
  // stage A: rows 0..7 (held by lanes kgr 0,1)
  if (kgr < 2) {
#pragma unroll
    for (int nt = 0; nt < 8; ++nt)
#pragma unroll
      for (int r = 0; r < 4; ++r)
        Pp[wave * 1024 + (kgr * 4 + r) * 128 + nt * 16 + nlo] = acc8[nt][r];
  }
  __syncthreads();
#pragma unroll
  for (int q = 0; q < 4; ++q) {
    int idx = q * 256 + tid;
    int pos = idx >> 7, o = idx & 127;
    float s = Pp[pos * 128 + o] + Pp[1024 + pos * 128 + o]
            + Pp[2048 + pos * 128 + o] + Pp[3072 + pos * 128 + o];
    float v = s + b_dc[o];
    v = fmaxf(s2[o] * v + t2[o], 0.f);
    P[pos * 152 + o] = bft(v);
  }
  __syncthreads();
  // stage B: rows 8..15 (held by lanes kgr 2,3)
  if (kgr >= 2) {
#pragma unroll
    for (int nt = 0; nt < 8; ++nt)
#pragma unroll
      for (int r = 0; r < 4; ++r)
        Pp[wave * 1024 + ((kgr - 2) * 4 + r) * 128 + nt * 16 + nlo] = acc8[nt][r];
  }
  __syncthreads();
#pragma unroll
  for (int q = 0; q < 4; ++q) {
    int idx = q * 256 + tid;
    int pos = idx >> 7, o = idx & 127;
    float s = Pp[pos * 128 + o] + Pp[1024 + pos * 128 + o]
            + Pp[2048 + pos * 128 + o] + Pp[3072 + pos * 128 + o];
    float v = s + b_dc[o];
    v = fmaxf(s2[o] * v + t2[o], 0.f);
    P[(8 + pos) * 152 + o] = bft(v);
  }
  __syncthreads();

  // ---- conv3 MFMA (M=16, K=128) from P ----
  float4v acc2[2];
  acc2[0] = (float4v)(0.f); acc2[1] = (float4v)(0.f);
  {
    const u16* b0p = &w3b[(((size_t)(wave * 2 + 0) * 4) * 64 + lane) * 8];
    const u16* b1p = &w3b[(((size_t)(wave * 2 + 1) * 4) * 64 + lane) * 8];
#pragma unroll
    for (int ks = 0; ks < 4; ++ks) {
      short8v a = *(const short8v*)&P[nlo * 152 + ks * 32 + kgr * 8];
      short8v b0 = *(const short8v*)(b0p + ks * 512);
      short8v b1 = *(const short8v*)(b1p + ks * 512);
      acc2[0] = __builtin_amdgcn_mfma_f32_16x16x32_bf16(a, b0, acc2[0], 0, 0, 0);
      acc2[1] = __builtin_amdgcn_mfma_f32_16x16x32_bf16(a, b1, acc2[1], 0, 0, 0);
    }
  }

  // bn3 chain -> T2[o][pos] (T2 overlays dead Pp; P region disjoint)
  const int rbase = kgr * 4;
#pragma unroll
  for (int nt = 0; nt < 2; ++nt) {
    int o = (wave * 2 + nt) * 16 + nlo;
    float sa = s3a[o], ta = t3a[o], sb = s3b[o], tb = t3b[o];
#pragma unroll
    for (int r = 0; r < 4; ++r) {
      float v = acc2[nt][r];
      v = fmaxf(sa * v + ta, 0.f);
      v = sb * v + tb;
      T2[o * 17 + rbase + r] = v;
    }
  }
  __syncthreads();

  // ---- transpose + ident + relu -> out NCHW fp32 ----
  {
    int o = tid >> 1, half = tid & 1;
    size_t g = ((size_t)((b * 128 + o) * 128 + h)) * 128 + wq * 16 + half * 8;
    const float* trow = &T2[o * 17 + half * 8];
    uint4 iv = *(const uint4*)&identb[g];
    u32 iw[4] = {iv.x, iv.y, iv.z, iv.w};
    float4 ov[2];
#pragma unroll
    for (int q = 0; q < 2; ++q) {
      float r0 = trow[q * 4 + 0] + bflo(iw[q * 2]);
      float r1 = trow[q * 4 + 1] + bfhi(iw[q * 2]);
      float r2 = trow[q * 4 + 2] + bflo(iw[q * 2 + 1]);
      float r3 = trow[q * 4 + 3] + bfhi(iw[q * 2 + 1]);
      ov[q] = make_float4(fmaxf(r0, 0.f), fmaxf(r1, 0.f), fmaxf(r2, 0.f), fmaxf(r3, 0.f));
    }
    *(float4*)&out[g] = ov[0];
    *(float4*)&out[g + 4] = ov[1];
  }
}

// ---------------------------------------------------------------------------
extern "C" void kernel_launch(void* const* d_in, const int* in_sizes, int n_in,
                              void* d_out, int out_size, void* d_ws, size_t ws_size,
                              hipStream_t stream) {
  const float* x     = (const float*)d_in[0];
  const float* w1    = (const float*)d_in[1];
  const float* s1a   = (const float*)d_in[2];
  const float* t1a   = (const float*)d_in[3];
  const float* s1b   = (const float*)d_in[4];
  const float* t1b   = (const float*)d_in[5];
  const float* w_off = (const float*)d_in[6];
  const float* b_off = (const float*)d_in[7];
  const float* w_dc  = (const float*)d_in[8];
  const float* b_dc  = (const float*)d_in[9];
  const float* s2    = (const float*)d_in[10];
  const float* t2    = (const float*)d_in[11];
  const float* w3    = (const float*)d_in[12];
  const float* s3a   = (const float*)d_in[13];
  const float* t3a   = (const float*)d_in[14];
  const float* s3b   = (const float*)d_in[15];
  const float* t3b   = (const float*)d_in[16];
  const float* w_ds  = (const float*)d_in[17];
  const float* b_ds  = (const float*)d_in[18];
  const float* sd    = (const float*)d_in[19];
  const float* td    = (const float*)d_in[20];

  char* ws = (char*)d_ws;
  u16* wTb    = (u16*)(ws + 0);            //    294,912 B
  u16* wB1    = (u16*)(ws + 294912);       //    131,072 B
  u16* w3b    = (u16*)(ws + 425984);       //     32,768 B
  u16* woffb  = (u16*)(ws + 458752);       //     73,728 B
  u16* out1   = (u16*)(ws + 532480);       // 16,777,216 B  NHWC bf16
  u16* identb = (u16*)(ws + 17309696);     // 16,777,216 B  NCHW bf16

  k_init  <<<1040, 256, 0, stream>>>(w_dc, w1, w_ds, w3, w_off, wTb, wB1, w3b, woffb);
  k_fused1<<<dim3(4, 128, 4), 256, 0, stream>>>(x, wB1, s1a, t1a, s1b, t1b, b_ds, sd, td, out1, identb);
  k_dcn   <<<dim3(8, 128, 4), 256, 0, stream>>>(out1, wTb, w3b, woffb, b_off, b_dc, s2, t2,
                                                s3a, t3a, s3b, t3b, identb, (float*)d_out);
}

// Round 7
// 287.057 us; speedup vs baseline: 1.0756x; 1.0756x over previous
//
#include <hip/hip_runtime.h>
#include <hip/hip_bf16.h>

#define HW 16384   // 128*128

typedef unsigned short u16;
typedef unsigned int   u32;
typedef __attribute__((ext_vector_type(8))) short short8v;
typedef __attribute__((ext_vector_type(4))) float float4v;

__device__ __forceinline__ float b2f(u16 v) { return __uint_as_float((u32)v << 16); }
__device__ __forceinline__ u16 f2bf(float f) {   // RNE (cold paths)
  u32 u = __float_as_uint(f);
  u32 r = (u + 0x7fffu + ((u >> 16) & 1u)) >> 16;
  return (u16)r;
}
__device__ __forceinline__ float bflo(u32 u) { return __uint_as_float(u << 16); }
__device__ __forceinline__ float bfhi(u32 u) { return __uint_as_float(u & 0xffff0000u); }
// 1-instruction truncating pack: (hi16(b)<<16)|hi16(a)  [v_perm_b32]
__device__ __forceinline__ u32 pkt(float a, float b) {
  return __builtin_amdgcn_perm(__float_as_uint(b), __float_as_uint(a), 0x07060302u);
}
__device__ __forceinline__ u16 bft(float v) { return (u16)(__float_as_uint(v) >> 16); }  // trunc

// ---------------------------------------------------------------------------
// K0: swizzle ALL weights into MFMA-B fragment order (bf16, RNE).
//  B-frag layout: buf[((ntile*KS + ks)*64 + lane)*8 + j]
//  with o = ntile*16 + (lane&15), k = ks*32 + (lane>>4)*8 + j.
// ---------------------------------------------------------------------------
__global__ __launch_bounds__(256) void k_init(const float* __restrict__ w_dc,
                                              const float* __restrict__ w1,
                                              const float* __restrict__ w_ds,
                                              const float* __restrict__ w3,
                                              const float* __restrict__ w_off,
                                              u16* __restrict__ wTb, u16* __restrict__ wB1,
                                              u16* __restrict__ w3b, u16* __restrict__ woffb) {
  int idx = blockIdx.x * 256 + threadIdx.x;
  if (idx < 147456) {
    int ntile = idx / 18432, r = idx % 18432;
    int ks = r / 512, r2 = r % 512;
    int lane = r2 / 8, j = r2 % 8;
    int o = ntile * 16 + (lane & 15);
    int k = ks * 32 + ((lane >> 4) * 8) + j;
    int tap = k >> 7, ci = k & 127;
    wTb[idx] = f2bf(w_dc[(o * 128 + ci) * 9 + tap]);
  }
  int i1 = idx - 147456;
  if (i1 >= 0 && i1 < 65536) {
    int ntile = i1 / 4096, r = i1 % 4096;
    int ks = r / 512, r2 = r % 512;
    int lane = r2 / 8, j = r2 % 8;
    int o = ntile * 16 + (lane & 15);
    int c = ks * 32 + ((lane >> 4) * 8) + j;
    float v = (ntile < 8) ? w1[o * 256 + c] : w_ds[(o - 128) * 256 + c];
    wB1[i1] = f2bf(v);
  }
  int i2 = idx - 212992;
  if (i2 >= 0 && i2 < 16384) {
    int ntile = i2 / 2048, r = i2 % 2048;
    int ks = r / 512, r2 = r % 512;
    int lane = r2 / 8, j = r2 % 8;
    int o = ntile * 16 + (lane & 15);
    int c = ks * 32 + ((lane >> 4) * 8) + j;
    w3b[i2] = f2bf(w3[o * 128 + c]);
  }
  int i3 = idx - 229376;
  if (i3 >= 0 && i3 < 36864) {
    int ntile = i3 / 18432, r = i3 % 18432;
    int ks = r / 512, r2 = r % 512;
    int lane = r2 / 8, j = r2 % 8;
    int oc = ntile * 16 + (lane & 15);
    int k = ks * 32 + ((lane >> 4) * 8) + j;
    int tap = k >> 7, c = k & 127;
    woffb[i3] = (oc < 27) ? f2bf(w_off[oc * 1152 + c * 9 + tap]) : (u16)0;
  }
}

// ---------------------------------------------------------------------------
// K1: fused conv1+downsample MFMA GEMM. M=32 pos, N=256, K=256.
// grid (4,128,4); block 256 = 4 waves. xA pitch 266 u16 (bank-clean).
// ---------------------------------------------------------------------------
__global__ __launch_bounds__(256) void k_fused1(const float* __restrict__ x,
                                                const u16* __restrict__ wB1,
                                                const float* __restrict__ s1a, const float* __restrict__ t1a,
                                                const float* __restrict__ s1b, const float* __restrict__ t1b,
                                                const float* __restrict__ b_ds,
                                                const float* __restrict__ sd, const float* __restrict__ td,
                                                u16* __restrict__ out1,      // [b][h][w][o]
                                                u16* __restrict__ identb)    // [b][o][h][w]
{
  __shared__ __align__(16) u16 xA[32 * 266];   // [pos][c] bf16, pitch 266
  __shared__ __align__(16) u16 T1[128 * 34];   // [o][pos] transpose buffer
  const int tid = threadIdx.x;
  const int wq = blockIdx.x, h = blockIdx.y, b = blockIdx.z;
  const int wave = tid >> 6, lane = tid & 63;

  {
    const float* xb = x + (size_t)b * 256 * HW + h * 128 + wq * 32;
    u32* dst = (u32*)xA;                 // u32 pitch 133 per pos row
    int cp = tid >> 3, wg = tid & 7;
#pragma unroll
    for (int i = 0; i < 4; ++i) {
      int cpair = i * 32 + cp;           // 0..127
      int c0 = cpair * 2;
      float4 va = *(const float4*)&xb[(size_t)c0 * HW + wg * 4];
      float4 vb = *(const float4*)&xb[(size_t)(c0 + 1) * HW + wg * 4];
      int p0 = wg * 4;
      dst[(p0 + 0) * 133 + cpair] = pkt(va.x, vb.x);
      dst[(p0 + 1) * 133 + cpair] = pkt(va.y, vb.y);
      dst[(p0 + 2) * 133 + cpair] = pkt(va.z, vb.z);
      dst[(p0 + 3) * 133 + cpair] = pkt(va.w, vb.w);
    }
  }
  __syncthreads();

  const int nlo = lane & 15, kgr = lane >> 4;
  float4v acc[2][4];
#pragma unroll
  for (int mt = 0; mt < 2; ++mt)
#pragma unroll
    for (int nt = 0; nt < 4; ++nt) acc[mt][nt] = (float4v)(0.f);

  const u16* a0p = &xA[nlo * 266 + kgr * 8];
  const u16* a1p = &xA[(nlo + 16) * 266 + kgr * 8];
  const u16* bp = &wB1[(((size_t)(wave * 4) * 8) * 64 + lane) * 8];

#pragma unroll
  for (int ks = 0; ks < 8; ++ks) {
    short8v a0 = *(const short8v*)(a0p + ks * 32);
    short8v a1 = *(const short8v*)(a1p + ks * 32);
#pragma unroll
    for (int nt = 0; nt < 4; ++nt) {
      short8v bv = *(const short8v*)(bp + nt * 4096 + ks * 512);
      acc[0][nt] = __builtin_amdgcn_mfma_f32_16x16x32_bf16(a0, bv, acc[0][nt], 0, 0, 0);
      acc[1][nt] = __builtin_amdgcn_mfma_f32_16x16x32_bf16(a1, bv, acc[1][nt], 0, 0, 0);
    }
  }

  const int rbase = kgr * 4;
  if (wave < 2) {
#pragma unroll
    for (int nt = 0; nt < 4; ++nt) {
      int o = (wave * 4 + nt) * 16 + nlo;
      float sa = s1a[o], ta = t1a[o], sb = s1b[o], tb = t1b[o];
#pragma unroll
      for (int mt = 0; mt < 2; ++mt)
#pragma unroll
        for (int r = 0; r < 4; ++r) {
          float v = acc[mt][nt][r];
          v = fmaxf(sa * v + ta, 0.f);
          v = fmaxf(sb * v + tb, 0.f);
          int pos = mt * 16 + rbase + r;
          out1[((size_t)((b * 128 + h) * 128 + wq * 32 + pos)) * 128 + o] = bft(v);
        }
    }
  } else {
#pragma unroll
    for (int nt = 0; nt < 4; ++nt) {
      int og = (wave * 4 + nt) * 16 + nlo - 128;
      float sv = sd[og], tv = td[og], bv = b_ds[og];
#pragma unroll
      for (int mt = 0; mt < 2; ++mt)
#pragma unroll
        for (int r = 0; r < 4; ++r) {
          float v = sv * (acc[mt][nt][r] + bv) + tv;
          T1[og * 34 + mt * 16 + rbase + r] = bft(v);
        }
    }
  }
  __syncthreads();

  {
    int o = tid >> 1, half = tid & 1;
    const u16* src = &T1[o * 34 + half * 16];
    u32 bb[8];
#pragma unroll
    for (int i = 0; i < 8; ++i) bb[i] = *(const u32*)(src + i * 2);
    size_t g = ((size_t)((b * 128 + o) * 128 + h)) * 128 + wq * 32 + half * 16;
    *(uint4*)&identb[g] = make_uint4(bb[0], bb[1], bb[2], bb[3]);
    *(uint4*)&identb[g + 8] = make_uint4(bb[4], bb[5], bb[6], bb[7]);
  }
}

// ---------------------------------------------------------------------------
// K2: MEGA-FUSED DCNv2, v8 — v7 (M=32 / 8 waves) with the divergent-barrier
//  bug fixed: A3 is now {predicated compute+write} -> ONE uniform barrier.
//  (Jl [0,9216) and offp [27744,44128) are disjoint, so no internal barrier
//  is needed; the post-A2 barrier protects W which Jl overlays.)
//  grid (4,128,4); block 512. LDS 44.2 KB -> 3 blocks/CU.
// ---------------------------------------------------------------------------
__global__ __launch_bounds__(512) void k_dcn(const u16* __restrict__ out1,
                                             const u16* __restrict__ wTb,
                                             const u16* __restrict__ w3b,
                                             const u16* __restrict__ woffb,
                                             const float* __restrict__ b_off,
                                             const float* __restrict__ b_dc,
                                             const float* __restrict__ s2, const float* __restrict__ t2,
                                             const float* __restrict__ s3a, const float* __restrict__ t3a,
                                             const float* __restrict__ s3b, const float* __restrict__ t3b,
                                             const u16* __restrict__ identb,
                                             float* __restrict__ out) {
  // Overlay map (44,160 B):
  //  A-phase : W [0,27744) = 102 rows x 136 u16 ; offp [27744,44128) 4x32x32 f32
  //  A3/loopB: jobtab [0,9216) = 288 jobs x 8 u32   (W dead after A2)
  //  reduce  : P [0,8704) 32x136 u16 ; Pp [9216,41984) 2 x 4096 f32
  //  conv3   : P + T2 [9216,26112) 128x33 f32       (Pp dead)
  __shared__ __align__(16) u16 U[22080];

  u16*   W    = U;                                  // pitch 136 u16
  float* offp = (float*)((char*)U + 27744);         // [kg][pos][oc32]
  u32*   Jl   = (u32*)U;                            // jobtab
  float* Pp   = (float*)((char*)U + 9216);          // [mh][ks][pos8][o]
  u16*   P    = U;                                  // [pos32][136]
  float* T2   = (float*)((char*)U + 9216);          // [o][33]

  const int tid = threadIdx.x;
  const int wq = blockIdx.x, h = blockIdx.y, b = blockIdx.z;
  const int wave = tid >> 6, lane = tid & 63;
  const int nlo = lane & 15, kgr = lane >> 4;
  const u16* base = out1 + (size_t)b * HW * 128;
  const int w0 = wq * 32;

  // ---- A1: stage window rows h-1..h+1, cols w0-1..w0+32 (102 px) ----
  for (int k = tid; k < 6528; k += 512) {           // 102 px * 64 u32
    int pix = k >> 6, cp = k & 63;
    int seg = pix / 34, col = pix % 34;
    int y = h - 1 + seg, x = w0 - 1 + col;
    u32 v = 0;
    if ((y >= 0) & (y < 128) & (x >= 0) & (x < 128))
      v = *(const u32*)&base[((size_t)(y * 128 + x)) * 128 + cp * 2];
    *((u32*)W + pix * 68 + cp) = v;
  }
  __syncthreads();

  // ---- A2: offset conv, 9 taps, K-split over 4 kg groups x 2 ntile ----
  {
    const int kg = wave >> 1, ntile = wave & 1;
    const int t0 = kg * 2, t1 = (kg == 3) ? 9 : kg * 2 + 2;
    float4v oacc[2];
    oacc[0] = (float4v)(0.f); oacc[1] = (float4v)(0.f);
    for (int t = t0; t < t1; ++t) {
      int ty = t / 3, tx = t % 3;
      const u16* bp = &woffb[(((size_t)(ntile * 36 + t * 4)) * 64 + lane) * 8];
#pragma unroll
      for (int ksl = 0; ksl < 4; ++ksl) {
        short8v bv = *(const short8v*)(bp + ksl * 512);
#pragma unroll
        for (int mt = 0; mt < 2; ++mt) {
          const u16* ap = &W[(ty * 34 + mt * 16 + nlo + tx) * 136 + ksl * 32 + kgr * 8];
          short8v a = *(const short8v*)ap;
          oacc[mt] = __builtin_amdgcn_mfma_f32_16x16x32_bf16(a, bv, oacc[mt], 0, 0, 0);
        }
      }
    }
    int oc = ntile * 16 + nlo;
#pragma unroll
    for (int mt = 0; mt < 2; ++mt)
#pragma unroll
      for (int r = 0; r < 4; ++r)
        offp[kg * 1024 + (mt * 16 + kgr * 4 + r) * 32 + oc] = oacc[mt][r];
  }
  __syncthreads();

  // ---- A3: per-job clamped corner offsets + weights -> jobtab ----
  // (predicated body, ONE uniform barrier after — no barrier inside)
  if (tid < 288) {
    int pos = tid / 9, tap = tid % 9;
    int w = w0 + pos;
    float dy  = offp[pos * 32 + tap]      + offp[1024 + pos * 32 + tap]
              + offp[2048 + pos * 32 + tap]      + offp[3072 + pos * 32 + tap]      + b_off[tap];
    float dxv = offp[pos * 32 + 9 + tap]  + offp[1024 + pos * 32 + 9 + tap]
              + offp[2048 + pos * 32 + 9 + tap]  + offp[3072 + pos * 32 + 9 + tap]  + b_off[9 + tap];
    float sg  = offp[pos * 32 + 18 + tap] + offp[1024 + pos * 32 + 18 + tap]
              + offp[2048 + pos * 32 + 18 + tap] + offp[3072 + pos * 32 + 18 + tap] + b_off[18 + tap];
    float mk = 1.f / (1.f + __expf(-sg));
    float py = (float)(h - 1 + tap / 3) + dy;
    float px = (float)(w - 1 + tap % 3) + dxv;
    float fy = floorf(py), fx = floorf(px);
    int y0 = (int)fy, x0 = (int)fx;
    float wy = py - fy, wxf = px - fx;
    bool vy0 = (y0 >= 0) & (y0 < 128), vy1 = (y0 >= -1) & (y0 < 127);
    bool vx0 = (x0 >= 0) & (x0 < 128), vx1 = (x0 >= -1) & (x0 < 127);
    float w00 = (vy0 & vx0) ? (1.f - wy) * (1.f - wxf) * mk : 0.f;
    float w01 = (vy0 & vx1) ? (1.f - wy) * wxf * mk : 0.f;
    float w10 = (vy1 & vx0) ? wy * (1.f - wxf) * mk : 0.f;
    float w11 = (vy1 & vx1) ? wy * wxf * mk : 0.f;
    int y0c = min(max(y0, 0), 127), y1c = min(max(y0 + 1, 0), 127);
    int x0c = min(max(x0, 0), 127), x1c = min(max(x0 + 1, 0), 127);
    u32* jt = &Jl[tid * 8];
    jt[0] = (u32)((y0c * 128 + x0c) * 128);
    jt[1] = (u32)((y0c * 128 + x1c) * 128);
    jt[2] = (u32)((y1c * 128 + x0c) * 128);
    jt[3] = (u32)((y1c * 128 + x1c) * 128);
    ((float*)jt)[4] = w00; ((float*)jt)[5] = w01;
    ((float*)jt)[6] = w10; ((float*)jt)[7] = w11;
  }
  __syncthreads();

  // ---- Loop B: DCN conv, K-split, barrier-free (v6-proven per-wave code) ----
  float4v acc8[8];
#pragma unroll
  for (int nt = 0; nt < 8; ++nt) acc8[nt] = (float4v)(0.f);
  {
    const int ks = wave & 3, mh = wave >> 2;
    const int ch0 = ks * 32 + kgr * 8;      // this lane's 8-channel group
    const int jrow = (mh * 16 + nlo) * 9;   // jobs of this lane's pos

    u32 gA[16], gB[16];
    float4 wA, wB;
    {
      uint4 co = *(const uint4*)&Jl[jrow * 8];
      wA = *(const float4*)&Jl[jrow * 8 + 4];
      uint4 v0 = *(const uint4*)(base + co.x + ch0);
      uint4 v1 = *(const uint4*)(base + co.y + ch0);
      uint4 v2 = *(const uint4*)(base + co.z + ch0);
      uint4 v3 = *(const uint4*)(base + co.w + ch0);
      gA[0] = v0.x; gA[1] = v0.y; gA[2] = v0.z; gA[3] = v0.w;
      gA[4] = v1.x; gA[5] = v1.y; gA[6] = v1.z; gA[7] = v1.w;
      gA[8] = v2.x; gA[9] = v2.y; gA[10] = v2.z; gA[11] = v2.w;
      gA[12] = v3.x; gA[13] = v3.y; gA[14] = v3.z; gA[15] = v3.w;
    }
#pragma unroll
    for (int t = 0; t < 9; ++t) {
      if (t < 8) {
        uint4 co = *(const uint4*)&Jl[(jrow + t + 1) * 8];
        if ((t & 1) == 0) {
          wB = *(const float4*)&Jl[(jrow + t + 1) * 8 + 4];
          uint4 v0 = *(const uint4*)(base + co.x + ch0);
          uint4 v1 = *(const uint4*)(base + co.y + ch0);
          uint4 v2 = *(const uint4*)(base + co.z + ch0);
          uint4 v3 = *(const uint4*)(base + co.w + ch0);
          gB[0] = v0.x; gB[1] = v0.y; gB[2] = v0.z; gB[3] = v0.w;
          gB[4] = v1.x; gB[5] = v1.y; gB[6] = v1.z; gB[7] = v1.w;
          gB[8] = v2.x; gB[9] = v2.y; gB[10] = v2.z; gB[11] = v2.w;
          gB[12] = v3.x; gB[13] = v3.y; gB[14] = v3.z; gB[15] = v3.w;
        } else {
          wA = *(const float4*)&Jl[(jrow + t + 1) * 8 + 4];
          uint4 v0 = *(const uint4*)(base + co.x + ch0);
          uint4 v1 = *(const uint4*)(base + co.y + ch0);
          uint4 v2 = *(const uint4*)(base + co.z + ch0);
          uint4 v3 = *(const uint4*)(base + co.w + ch0);
          gA[0] = v0.x; gA[1] = v0.y; gA[2] = v0.z; gA[3] = v0.w;
          gA[4] = v1.x; gA[5] = v1.y; gA[6] = v1.z; gA[7] = v1.w;
          gA[8] = v2.x; gA[9] = v2.y; gA[10] = v2.z; gA[11] = v2.w;
          gA[12] = v3.x; gA[13] = v3.y; gA[14] = v3.z; gA[15] = v3.w;
        }
      }
      union { u32 u[4]; short8v s; } av;
      {
        const u32* g = ((t & 1) == 0) ? gA : gB;
        float4 w = ((t & 1) == 0) ? wA : wB;
#pragma unroll
        for (int p = 0; p < 4; ++p) {
          float alo = w.x * bflo(g[p])      + w.y * bflo(g[4 + p])
                    + w.z * bflo(g[8 + p])  + w.w * bflo(g[12 + p]);
          float ahi = w.x * bfhi(g[p])      + w.y * bfhi(g[4 + p])
                    + w.z * bfhi(g[8 + p])  + w.w * bfhi(g[12 + p]);
          av.u[p] = pkt(alo, ahi);
        }
      }
      {
        const u16* bb = &wTb[(((size_t)(t * 4 + ks)) * 64 + lane) * 8];
#pragma unroll
        for (int nt = 0; nt < 8; ++nt) {
          short8v bv = *(const short8v*)(bb + (size_t)nt * 18432);
          acc8[nt] = __builtin_amdgcn_mfma_f32_16x16x32_bf16(av.s, bv, acc8[nt], 0, 0, 0);
        }
      }
    }
  }
  __syncthreads();   // jobtab dead; U reusable

  // ---- Reduction: per-mh-group combine of 4 K-partials + bn2 -> P ----
  {
    const int ks = wave & 3, mh = wave >> 2;
    // stage A: local pos 0..7 (kgr 0,1)
    if (kgr < 2) {
#pragma unroll
      for (int nt = 0; nt < 8; ++nt)
#pragma unroll
        for (int r = 0; r < 4; ++r)
          Pp[mh * 4096 + ks * 1024 + (kgr * 4 + r) * 128 + nt * 16 + nlo] = acc8[nt][r];
    }
    __syncthreads();
#pragma unroll
    for (int q = 0; q < 4; ++q) {
      int idx = q * 512 + tid;
      int mi = idx >> 10, rem = idx & 1023;
      int p8 = rem >> 7, o = rem & 127;
      const float* Pb = Pp + mi * 4096 + p8 * 128 + o;
      float s = Pb[0] + Pb[1024] + Pb[2048] + Pb[3072];
      float v = s + b_dc[o];
      v = fmaxf(s2[o] * v + t2[o], 0.f);
      P[(mi * 16 + p8) * 136 + o] = bft(v);
    }
    __syncthreads();
    // stage B: local pos 8..15 (kgr 2,3)
    if (kgr >= 2) {
#pragma unroll
      for (int nt = 0; nt < 8; ++nt)
#pragma unroll
        for (int r = 0; r < 4; ++r)
          Pp[mh * 4096 + ks * 1024 + ((kgr - 2) * 4 + r) * 128 + nt * 16 + nlo] = acc8[nt][r];
    }
    __syncthreads();
#pragma unroll
    for (int q = 0; q < 4; ++q) {
      int idx = q * 512 + tid;
      int mi = idx >> 10, rem = idx & 1023;
      int p8 = rem >> 7, o = rem & 127;
      const float* Pb = Pp + mi * 4096 + p8 * 128 + o;
      float s = Pb[0] + Pb[1024] + Pb[2048] + Pb[3072];
      float v = s + b_dc[o];
      v = fmaxf(s2[o] * v + t2[o], 0.f);
      P[(mi * 16 + 8 + p8) * 136 + o] = bft(v);
    }
    __syncthreads();
  }

  // ---- conv3 MFMA (M=32, K=128): wave owns o-tile = wave, both m-tiles ----
  float4v acc2[2];
  acc2[0] = (float4v)(0.f); acc2[1] = (float4v)(0.f);
  {
    const u16* bp3 = &w3b[(((size_t)(wave * 4)) * 64 + lane) * 8];
#pragma unroll
    for (int ks3 = 0; ks3 < 4; ++ks3) {
      short8v bv = *(const short8v*)(bp3 + ks3 * 512);
#pragma unroll
      for (int mt = 0; mt < 2; ++mt) {
        short8v a = *(const short8v*)&P[(mt * 16 + nlo) * 136 + ks3 * 32 + kgr * 8];
        acc2[mt] = __builtin_amdgcn_mfma_f32_16x16x32_bf16(a, bv, acc2[mt], 0, 0, 0);
      }
    }
  }

  // bn3 chain -> T2[o][pos33] (overlays dead Pp; P region disjoint)
  {
    int o = wave * 16 + nlo;
    float sa = s3a[o], ta = t3a[o], sb = s3b[o], tb = t3b[o];
#pragma unroll
    for (int mt = 0; mt < 2; ++mt)
#pragma unroll
      for (int r = 0; r < 4; ++r) {
        float v = acc2[mt][r];
        v = fmaxf(sa * v + ta, 0.f);
        v = sb * v + tb;
        T2[o * 33 + mt * 16 + kgr * 4 + r] = v;
      }
  }
  __syncthreads();

  // ---- transpose + ident + relu -> out NCHW fp32 ----
  {
    int o = tid >> 2, qd = tid & 3;
    size_t g = ((size_t)((b * 128 + o) * 128 + h)) * 128 + w0 + qd * 8;
    const float* trow = &T2[o * 33 + qd * 8];
    uint4 iv = *(const uint4*)&identb[g];
    u32 iw[4] = {iv.x, iv.y, iv.z, iv.w};
    float4 ov[2];
#pragma unroll
    for (int q = 0; q < 2; ++q) {
      float r0 = trow[q * 4 + 0] + bflo(iw[q * 2]);
      float r1 = trow[q * 4 + 1] + bfhi(iw[q * 2]);
      float r2 = trow[q * 4 + 2] + bflo(iw[q * 2 + 1]);
      float r3 = trow[q * 4 + 3] + bfhi(iw[q * 2 + 1]);
      ov[q] = make_float4(fmaxf(r0, 0.f), fmaxf(r1, 0.f), fmaxf(r2, 0.f), fmaxf(r3, 0.f));
    }
    *(float4*)&out[g] = ov[0];
    *(float4*)&out[g + 4] = ov[1];
  }
}

// ---------------------------------------------------------------------------
extern "C" void kernel_launch(void* const* d_in, const int* in_sizes, int n_in,
                              void* d_out, int out_size, void* d_ws, size_t ws_size,
                              hipStream_t stream) {
  const float* x     = (const float*)d_in[0];
  const float* w1    = (const float*)d_in[1];
  const float* s1a   = (const float*)d_in[2];
  const float* t1a   = (const float*)d_in[3];
  const float* s1b   = (const float*)d_in[4];
  const float* t1b   = (const float*)d_in[5];
  const float* w_off = (const float*)d_in[6];
  const float* b_off = (const float*)d_in[7];
  const float* w_dc  = (const float*)d_in[8];
  const float* b_dc  = (const float*)d_in[9];
  const float* s2    = (const float*)d_in[10];
  const float* t2    = (const float*)d_in[11];
  const float* w3    = (const float*)d_in[12];
  const float* s3a   = (const float*)d_in[13];
  const float* t3a   = (const float*)d_in[14];
  const float* s3b   = (const float*)d_in[15];
  const float* t3b   = (const float*)d_in[16];
  const float* w_ds  = (const float*)d_in[17];
  const float* b_ds  = (const float*)d_in[18];
  const float* sd    = (const float*)d_in[19];
  const float* td    = (const float*)d_in[20];

  char* ws = (char*)d_ws;
  u16* wTb    = (u16*)(ws + 0);            //    294,912 B
  u16* wB1    = (u16*)(ws + 294912);       //    131,072 B
  u16* w3b    = (u16*)(ws + 425984);       //     32,768 B
  u16* woffb  = (u16*)(ws + 458752);       //     73,728 B
  u16* out1   = (u16*)(ws + 532480);       // 16,777,216 B  NHWC bf16
  u16* identb = (u16*)(ws + 17309696);     // 16,777,216 B  NCHW bf16

  k_init  <<<1040, 256, 0, stream>>>(w_dc, w1, w_ds, w3, w_off, wTb, wB1, w3b, woffb);
  k_fused1<<<dim3(4, 128, 4), 256, 0, stream>>>(x, wB1, s1a, t1a, s1b, t1b, b_ds, sd, td, out1, identb);
  k_dcn   <<<dim3(4, 128, 4), 512, 0, stream>>>(out1, wTb, w3b, woffb, b_off, b_dc, s2, t2,
                                                s3a, t3a, s3b, t3b, identb, (float*)d_out);
}